// Round 8
// baseline (103.904 us; speedup 1.0000x reference)
//
#include <hip/hip_runtime.h>
#include <math.h>

// B=4, T=S=512, M=N=512, H=128
#define KDIM 512
#define HDIM 128
#define SDIM 512
#define ROWS 16          // rows per proj block
#define TOTAL_ROWS 2048  // B*T == B*S
#define PROJ_REPS 8      // DIAGNOSTIC: repeat proj work to surface it in rocprof top-5

// score[b,t,s] = ( a[b,t] + c[b,s] ) / sqrt(512); separable projections.

__device__ __forceinline__ float fast_tanh(float x) {
    float e = __expf(2.0f * x);
    return 1.0f - 2.0f / (e + 1.0f);
}

// Champion round-2 structure, body repeated `reps` times (identical output).
__global__ __launch_bounds__(512, 2) void proj_kernel(
    const float* __restrict__ query, const float* __restrict__ keys,
    const float* __restrict__ W1, const float* __restrict__ W2,
    const float* __restrict__ v, float* __restrict__ ws, int reps)
{
    const int blk = blockIdx.x;
    const int bpt = TOTAL_ROWS / ROWS;  // 128
    const bool is_keys = (blk >= bpt);
    const float* __restrict__ X  = is_keys ? keys : query;
    const float* __restrict__ W  = is_keys ? W1 : W2;
    const float* __restrict__ vv = v + (is_keys ? HDIM : 0);
    float* __restrict__ out = ws + (is_keys ? TOTAL_ROWS : 0);
    const int row0 = (is_keys ? (blk - bpt) : blk) * ROWS;

    __shared__ float sm_x[ROWS][KDIM];   // 32 KB
    __shared__ float sm_p[8][8];         // [wave][r] partials

    const int tid  = threadIdx.x;
    const int ks   = tid & 7;          // K-split slot (lane bits 0-2)
    const int hg   = (tid >> 3) & 31;  // h-group: 4 h's each
    const int rowg = tid >> 8;         // row half: 8 rows each

    for (int it = 0; it < reps; ++it) {
        // opaque zero: prevents cross-iteration CSE of the whole body
        int z;
        asm volatile("v_mov_b32 %0, 0" : "=v"(z));
        const float* __restrict__ Xe = X + z;
        const float* __restrict__ We = W + z;

        // Stage X tile: ROWS*KDIM = 8192 floats = 2048 float4; 512 threads x 4
        {
            const float4* __restrict__ src = (const float4*)(Xe + (size_t)row0 * KDIM);
            float4* dst = (float4*)(&sm_x[0][0]);
            #pragma unroll
            for (int i = 0; i < 4; ++i)
                dst[tid + i * 512] = src[tid + i * 512];
        }
        __syncthreads();

        float acc[8][4];
        #pragma unroll
        for (int r = 0; r < 8; ++r)
            #pragma unroll
            for (int hh = 0; hh < 4; ++hh) acc[r][hh] = 0.0f;

        const float* __restrict__ wbase = We + (size_t)(hg * 4) * KDIM;
        const float* __restrict__ xbase = &sm_x[rowg * 8][0];

        #pragma unroll 2
        for (int jj = 0; jj < 16; ++jj) {
            const int col = jj * 32 + ks * 4;
            const float4 w0 = *(const float4*)(wbase + 0 * KDIM + col);
            const float4 w1 = *(const float4*)(wbase + 1 * KDIM + col);
            const float4 w2 = *(const float4*)(wbase + 2 * KDIM + col);
            const float4 w3 = *(const float4*)(wbase + 3 * KDIM + col);
            #pragma unroll
            for (int r = 0; r < 8; ++r) {
                const float4 x = *(const float4*)(xbase + r * KDIM + col);
                acc[r][0] = fmaf(x.x, w0.x, acc[r][0]);
                acc[r][0] = fmaf(x.y, w0.y, acc[r][0]);
                acc[r][0] = fmaf(x.z, w0.z, acc[r][0]);
                acc[r][0] = fmaf(x.w, w0.w, acc[r][0]);
                acc[r][1] = fmaf(x.x, w1.x, acc[r][1]);
                acc[r][1] = fmaf(x.y, w1.y, acc[r][1]);
                acc[r][1] = fmaf(x.z, w1.z, acc[r][1]);
                acc[r][1] = fmaf(x.w, w1.w, acc[r][1]);
                acc[r][2] = fmaf(x.x, w2.x, acc[r][2]);
                acc[r][2] = fmaf(x.y, w2.y, acc[r][2]);
                acc[r][2] = fmaf(x.z, w2.z, acc[r][2]);
                acc[r][2] = fmaf(x.w, w2.w, acc[r][2]);
                acc[r][3] = fmaf(x.x, w3.x, acc[r][3]);
                acc[r][3] = fmaf(x.y, w3.y, acc[r][3]);
                acc[r][3] = fmaf(x.z, w3.z, acc[r][3]);
                acc[r][3] = fmaf(x.w, w3.w, acc[r][3]);
            }
        }

        // K-split reduce over ks (lane bits 0-2)
        #pragma unroll
        for (int r = 0; r < 8; ++r)
            #pragma unroll
            for (int hh = 0; hh < 4; ++hh) {
                float s = acc[r][hh];
                s += __shfl_xor(s, 1, 64);
                s += __shfl_xor(s, 2, 64);
                s += __shfl_xor(s, 4, 64);
                acc[r][hh] = s;
            }

        const float4 vh = *(const float4*)(vv + hg * 4);
        const int wave = tid >> 6;
        const int lane = tid & 63;
        #pragma unroll
        for (int r = 0; r < 8; ++r) {
            float rs = vh.x * fast_tanh(acc[r][0]) + vh.y * fast_tanh(acc[r][1])
                     + vh.z * fast_tanh(acc[r][2]) + vh.w * fast_tanh(acc[r][3]);
            rs += __shfl_xor(rs, 8, 64);
            rs += __shfl_xor(rs, 16, 64);
            rs += __shfl_xor(rs, 32, 64);
            if (lane == 0) sm_p[wave][r] = rs;
        }
        __syncthreads();

        if (tid < ROWS) {
            const int rg = tid >> 3, r = tid & 7;
            const float s = sm_p[rg * 4 + 0][r] + sm_p[rg * 4 + 1][r]
                          + sm_p[rg * 4 + 2][r] + sm_p[rg * 4 + 3][r];
            out[row0 + tid] = s;
        }
        __syncthreads();
        asm volatile("" ::: "memory");
    }
}

__global__ __launch_bounds__(128) void outer_kernel(
    const float* __restrict__ ws, float* __restrict__ out)
{
    const int bt = blockIdx.x;                  // 0..2047
    const float a = ws[bt];
    const int b = bt >> 9;                      // / T
    const float4* __restrict__ c4 = (const float4*)(ws + TOTAL_ROWS + (size_t)b * SDIM);
    const float inv_scale = 0.04419417382415922f;  // 1/sqrt(512)

    const float4 cv = c4[threadIdx.x];
    float4 o;
    o.x = (a + cv.x) * inv_scale;
    o.y = (a + cv.y) * inv_scale;
    o.z = (a + cv.z) * inv_scale;
    o.w = (a + cv.w) * inv_scale;
    ((float4*)out)[(size_t)bt * (SDIM / 4) + threadIdx.x] = o;
}

extern "C" void kernel_launch(void* const* d_in, const int* in_sizes, int n_in,
                              void* d_out, int out_size, void* d_ws, size_t ws_size,
                              hipStream_t stream) {
    const float* query = (const float*)d_in[0];  // (4,512,512)
    const float* keys  = (const float*)d_in[1];  // (4,512,512)
    const float* W1    = (const float*)d_in[2];  // (128,512)
    const float* W2    = (const float*)d_in[3];  // (128,512)
    const float* v     = (const float*)d_in[4];  // (1,256)
    float* out = (float*)d_out;                  // (4,512,512) f32
    float* ws  = (float*)d_ws;                   // a (2048) + c (2048) floats

    proj_kernel<<<2 * (TOTAL_ROWS / ROWS), 512, 0, stream>>>(query, keys, W1, W2, v, ws, PROJ_REPS);
    outer_kernel<<<TOTAL_ROWS, 128, 0, stream>>>(ws, out);
}

// Round 9
// 23.246 us; speedup vs baseline: 4.4698x; 4.4698x over previous
//
#include <hip/hip_runtime.h>
#include <hip/hip_bf16.h>
#include <math.h>

// B=4, T=S=512, M=N=512, H=128
#define KDIM 512
#define HDIM 128
#define SDIM 512
#define TOTAL_ROWS 2048
#define INV_SCALE 0.04419417382415922f   // 1/sqrt(512)

// score[b,t,s] = a'[b,t] + c'[b,s]  (both pre-scaled)
//   a'[b,t] = inv_scale * sum_h v[h]   * tanh(q[b,t,:]·W2[h,:])
//   c'[b,s] = inv_scale * sum_h v[H+h] * tanh(k[b,s,:]·W1[h,:])

typedef __attribute__((ext_vector_type(8))) short bf16x8;   // 8 bf16 = 4 VGPRs
typedef __attribute__((ext_vector_type(4))) float f32x4;    // MFMA accumulator

__device__ __forceinline__ float fast_tanh(float x) {
    // tanh(x) = 1 - 2/(e^{2x}+1); ~1e-7 abs error, graceful at +/-inf
    float e = __expf(2.0f * x);
    return 1.0f - 2.0f / (e + 1.0f);
}

__device__ __forceinline__ short bf16bits(float x) {
    return __builtin_bit_cast(short, __float2bfloat16(x));
}

// 256 blocks x 512 threads (8 waves). blocks [0,128): query -> ws[0:2048];
// [128,256): keys -> ws[2048:4096]. Block = 16 rows; wave w owns h-tile h0 = 16w.
// MFMA 16x16x32: lane holds A row (row0 + lane&15), B col (h0 + lane&15),
// k-slots (lane>>4)*8..+8 per step (A/B use the same mapping, so any k-bijection
// cancels). C: col = lane&15 (h), row = (lane>>4)*4 + reg (HW-verified m89/m91).
// No LDS staging: A/B loaded 32B contiguous from global, cvt to bf16 in-register.
__global__ __launch_bounds__(512) void proj_kernel(
    const float* __restrict__ query, const float* __restrict__ keys,
    const float* __restrict__ W1, const float* __restrict__ W2,
    const float* __restrict__ v, float* __restrict__ ws)
{
    const int blk = blockIdx.x;           // 0..255
    const bool is_keys = (blk >= 128);
    const float* __restrict__ X  = is_keys ? keys : query;
    const float* __restrict__ W  = is_keys ? W1 : W2;
    const float* __restrict__ vv = v + (is_keys ? HDIM : 0);
    float* __restrict__ out = ws + (is_keys ? TOTAL_ROWS : 0);
    const int row0 = (is_keys ? blk - 128 : blk) * 16;

    __shared__ float sm_p[8][16];         // [wave][row] partial sums

    const int tid  = threadIdx.x;         // 0..511
    const int wave = tid >> 6;            // 0..7 -> h-tile
    const int lane = tid & 63;
    const int c16  = lane & 15;           // A row / B col within tile
    const int g    = lane >> 4;           // k-group 0..3 (8 k each)
    const int h0   = wave * 16;

    const float* __restrict__ xrow = X + (size_t)(row0 + c16) * KDIM + g * 8;
    const float* __restrict__ wrow = W + (size_t)(h0 + c16) * KDIM + g * 8;

    f32x4 acc = {0.0f, 0.0f, 0.0f, 0.0f};

    // 16 K-steps of 32; per step each lane: 2x16B X + 2x16B W, cvt, 1 MFMA.
    #pragma unroll 4
    for (int t = 0; t < 16; ++t) {
        const float4 a0 = *(const float4*)(xrow + t * 32);
        const float4 a1 = *(const float4*)(xrow + t * 32 + 4);
        const float4 b0 = *(const float4*)(wrow + t * 32);
        const float4 b1 = *(const float4*)(wrow + t * 32 + 4);
        bf16x8 a, b;
        a[0] = bf16bits(a0.x); a[1] = bf16bits(a0.y);
        a[2] = bf16bits(a0.z); a[3] = bf16bits(a0.w);
        a[4] = bf16bits(a1.x); a[5] = bf16bits(a1.y);
        a[6] = bf16bits(a1.z); a[7] = bf16bits(a1.w);
        b[0] = bf16bits(b0.x); b[1] = bf16bits(b0.y);
        b[2] = bf16bits(b0.z); b[3] = bf16bits(b0.w);
        b[4] = bf16bits(b1.x); b[5] = bf16bits(b1.y);
        b[6] = bf16bits(b1.z); b[7] = bf16bits(b1.w);
        acc = __builtin_amdgcn_mfma_f32_16x16x32_bf16(a, b, acc, 0, 0, 0);
    }

    // Epilogue: acc[r] = dot(X[row0 + g*4 + r], W[h0 + c16]).
    const float vh = vv[h0 + c16];
    float val[4];
    #pragma unroll
    for (int r = 0; r < 4; ++r) {
        float s = vh * fast_tanh(acc[r]);
        // sum over the 16 h-columns (lane bits 0-3)
        s += __shfl_xor(s, 1, 64);
        s += __shfl_xor(s, 2, 64);
        s += __shfl_xor(s, 4, 64);
        s += __shfl_xor(s, 8, 64);
        val[r] = s;
    }
    if (c16 == 0) {
        #pragma unroll
        for (int r = 0; r < 4; ++r) sm_p[wave][g * 4 + r] = val[r];
    }
    __syncthreads();

    if (tid < 16) {
        float s = 0.0f;
        #pragma unroll
        for (int w = 0; w < 8; ++w) s += sm_p[w][tid];
        out[row0 + tid] = s * INV_SCALE;
    }
}

__global__ __launch_bounds__(128) void outer_kernel(
    const float* __restrict__ ws, float* __restrict__ out)
{
    // block = b*T + t; threads cover S=512 via float4
    const int bt = blockIdx.x;                  // 0..2047
    const float a = ws[bt];
    const int b = bt >> 9;                      // / T
    const float4* __restrict__ c4 = (const float4*)(ws + TOTAL_ROWS + (size_t)b * SDIM);

    const float4 cv = c4[threadIdx.x];
    float4 o;
    o.x = a + cv.x;
    o.y = a + cv.y;
    o.z = a + cv.z;
    o.w = a + cv.w;
    ((float4*)out)[(size_t)bt * (SDIM / 4) + threadIdx.x] = o;
}

extern "C" void kernel_launch(void* const* d_in, const int* in_sizes, int n_in,
                              void* d_out, int out_size, void* d_ws, size_t ws_size,
                              hipStream_t stream) {
    const float* query = (const float*)d_in[0];  // (4,512,512)
    const float* keys  = (const float*)d_in[1];  // (4,512,512)
    const float* W1    = (const float*)d_in[2];  // (128,512)
    const float* W2    = (const float*)d_in[3];  // (128,512)
    const float* v     = (const float*)d_in[4];  // (1,256)
    float* out = (float*)d_out;                  // (4,512,512) f32
    float* ws  = (float*)d_ws;                   // a' (2048) + c' (2048) floats

    proj_kernel<<<256, 512, 0, stream>>>(query, keys, W1, W2, v, ws);
    outer_kernel<<<TOTAL_ROWS, 128, 0, stream>>>(ws, out);
}

// Round 10
// 18.578 us; speedup vs baseline: 5.5929x; 1.2513x over previous
//
#include <hip/hip_runtime.h>
#include <hip/hip_bf16.h>
#include <math.h>

// B=4, T=S=512, M=N=512, H=128
#define KDIM 512
#define HDIM 128
#define SDIM 512
#define TOTAL_ROWS 2048
#define INV_SCALE 0.04419417382415922f   // 1/sqrt(512)

// ws layout (bytes):
//   [0, 8192)        a' f32[2048]   (query side)
//   [8192, 16384)    c' f32[2048]   (keys side)
//   [16384, 147456)  W1 bf16 [128][512]
//   [147456, 278528) W2 bf16 [128][512]
#define WB_OFF_F32 4096   // ws float-index where bf16 W region starts

typedef __attribute__((ext_vector_type(8))) short bf16x8;   // 8 bf16 = 4 VGPRs
typedef __attribute__((ext_vector_type(4))) float f32x4;    // MFMA accumulator

__device__ __forceinline__ float fast_tanh(float x) {
    // tanh(x) = 1 - 2/(e^{2x}+1); ~1e-7 abs error, graceful at +/-inf
    float e = __expf(2.0f * x);
    return 1.0f - 2.0f / (e + 1.0f);
}
__device__ __forceinline__ unsigned short bfbits(float x) {
    return __builtin_bit_cast(unsigned short, __float2bfloat16(x));
}

// W1,W2 f32 -> bf16 into ws. 128 blocks x 256 thr, one float4 -> ushort4 each.
// Output region is contiguous: idx<16384 -> W1b, else W2b.
__global__ __launch_bounds__(256) void wcvt_kernel(
    const float* __restrict__ W1, const float* __restrict__ W2,
    unsigned short* __restrict__ wb)
{
    const int idx = blockIdx.x * 256 + threadIdx.x;          // 0..32767
    const float4 w = (idx < 16384) ? ((const float4*)W1)[idx]
                                   : ((const float4*)W2)[idx - 16384];
    ushort4 o;
    o.x = bfbits(w.x); o.y = bfbits(w.y); o.z = bfbits(w.z); o.w = bfbits(w.w);
    ((ushort4*)wb)[idx] = o;
}

// 256 blocks x 512 thr (8 waves). blk<128: query w/ W2b, v[0:128] -> ws[0:2048);
// blk>=128: keys w/ W1b, v[128:256] -> ws[2048:4096). Block = 16 rows; wave = h-tile.
// X-tile staged in LDS as bf16 [16][512], 16B slots XOR-swizzled: slot ^= (row&7)
// (even bank spread for ds_write_b64 staging and ds_read_b128 frags).
// B-frags read from pre-converted bf16 W: one dwordx4 covers 16 rows x 64B fully used.
// MFMA 16x16x32_bf16, k-slot (lane>>4)*8 identical on A and B (bijection cancels);
// C: col=lane&15 (h), row=(lane>>4)*4+reg (verified r9/m89).
__global__ __launch_bounds__(512) void proj_kernel(
    const float* __restrict__ query, const float* __restrict__ keys,
    const unsigned short* __restrict__ wb, const float* __restrict__ v,
    float* __restrict__ ws)
{
    const int blk = blockIdx.x;
    const bool is_keys = (blk >= 128);
    const float* __restrict__ X = is_keys ? keys : query;
    const unsigned short* __restrict__ Wb = wb + (is_keys ? 0 : 65536); // W1b | W2b
    const float* __restrict__ vv = v + (is_keys ? HDIM : 0);
    float* __restrict__ out = ws + (is_keys ? TOTAL_ROWS : 0);
    const int row0 = (blk & 127) * 16;

    __shared__ __align__(16) unsigned short sm_x[16 * KDIM];  // 16 KB bf16
    __shared__ float sm_p[8][16];

    const int tid  = threadIdx.x;
    const int wave = tid >> 6;
    const int lane = tid & 63;

    // ---- Stage X tile: wave handles rows {wave, 8+wave}; per pass a contiguous
    // float4 load (64 lanes = 1KB), cvt to 4 bf16, ds_write_b64 swizzled. ----
    #pragma unroll
    for (int it = 0; it < 2; ++it) {
        const int row = it * 8 + wave;
        const float4* __restrict__ src = (const float4*)(X + (size_t)(row0 + row) * KDIM);
        #pragma unroll
        for (int p = 0; p < 2; ++p) {
            const float4 xv = src[p * 64 + lane];
            ushort4 o;
            o.x = bfbits(xv.x); o.y = bfbits(xv.y);
            o.z = bfbits(xv.z); o.w = bfbits(xv.w);
            const int sl   = p * 32 + (lane >> 1);     // 16B slot in row
            const int half = lane & 1;                 // low/high 8B of slot
            char* dst = (char*)sm_x + row * 1024 + ((sl ^ (row & 7)) << 4) + half * 8;
            *(ushort4*)dst = o;
        }
    }
    __syncthreads();

    // ---- MFMA: wave's h-tile h0 = wave*16; 16 K-steps of 32. ----
    const int c16 = lane & 15;
    const int g   = lane >> 4;
    const int h0  = wave * 16;
    const unsigned short* __restrict__ wrow = Wb + (size_t)(h0 + c16) * KDIM + g * 8;
    const char* __restrict__ arow = (const char*)sm_x + c16 * 1024;
    const int swz = c16 & 7;

    f32x4 acc = {0.0f, 0.0f, 0.0f, 0.0f};
    #pragma unroll 4
    for (int t = 0; t < 16; ++t) {
        const bf16x8 a = *(const bf16x8*)(arow + (((t * 4 + g) ^ swz) << 4));
        const bf16x8 b = *(const bf16x8*)(wrow + t * 32);
        acc = __builtin_amdgcn_mfma_f32_16x16x32_bf16(a, b, acc, 0, 0, 0);
    }

    // ---- Epilogue: acc[r] = dot(X[row0+g*4+r], W[h0+c16]); weight, tanh, reduce. ----
    const float vh = vv[h0 + c16];
    #pragma unroll
    for (int r = 0; r < 4; ++r) {
        float s = vh * fast_tanh(acc[r]);
        s += __shfl_xor(s, 1, 64);
        s += __shfl_xor(s, 2, 64);
        s += __shfl_xor(s, 4, 64);
        s += __shfl_xor(s, 8, 64);
        if (c16 == 0) sm_p[wave][g * 4 + r] = s;
    }
    __syncthreads();

    if (tid < 16) {
        float s = 0.0f;
        #pragma unroll
        for (int w = 0; w < 8; ++w) s += sm_p[w][tid];
        out[row0 + tid] = s * INV_SCALE;
    }
}

// 256 blocks x 256 thr; block = 8 bt-rows (one batch). c' row stays L1-hot.
__global__ __launch_bounds__(256) void outer_kernel(
    const float* __restrict__ ws, float* __restrict__ out)
{
    const int r0  = blockIdx.x * 8;
    const int b   = r0 >> 9;
    const float4* __restrict__ c4 = (const float4*)(ws + TOTAL_ROWS + (size_t)b * SDIM);
    const int col = threadIdx.x & 127;
    const int rh  = threadIdx.x >> 7;   // 0/1

    #pragma unroll
    for (int rp = 0; rp < 4; ++rp) {
        const int row = r0 + rp * 2 + rh;
        const float a = ws[row];
        const float4 c = c4[col];
        float4 o;
        o.x = a + c.x; o.y = a + c.y; o.z = a + c.z; o.w = a + c.w;
        ((float4*)out)[(size_t)row * (SDIM / 4) + col] = o;
    }
}

extern "C" void kernel_launch(void* const* d_in, const int* in_sizes, int n_in,
                              void* d_out, int out_size, void* d_ws, size_t ws_size,
                              hipStream_t stream) {
    const float* query = (const float*)d_in[0];  // (4,512,512)
    const float* keys  = (const float*)d_in[1];  // (4,512,512)
    const float* W1    = (const float*)d_in[2];  // (128,512)
    const float* W2    = (const float*)d_in[3];  // (128,512)
    const float* v     = (const float*)d_in[4];  // (1,256)
    float* out = (float*)d_out;                  // (4,512,512) f32
    float* ws  = (float*)d_ws;
    unsigned short* wb = (unsigned short*)(ws + WB_OFF_F32);

    wcvt_kernel<<<128, 256, 0, stream>>>(W1, W2, wb);
    proj_kernel<<<256, 512, 0, stream>>>(query, keys, wb, v, ws);
    outer_kernel<<<256, 256, 0, stream>>>(ws, out);
}